// Round 8
// baseline (203.276 us; speedup 1.0000x reference)
//
#include <hip/hip_runtime.h>

// VectorQuantizer, fused: gemm reads z directly (transpose+f16-split in-kernel).
//   wh = f16(16*w_hat), wl = f16(16*w_hat - wh)   (uniform x16: argmax-invariant)
//   zh = f16(4*z),      zl = f16(4*z - zh)        (uniform x4:  argmax-invariant)
//   dot64 = hh + hl + lh  (single f32 accumulator chain; ll ~2^-22 rel, dropped)
// argmin_k ||z_hat - w_hat_k|| == argmax_k <z, w_hat_k>  -> only codebook normalized.
//
// R7: occupancy push. Wave tile 64x32 (acc 32 regs), block tile 128x64,
//   16 n-tile blocks (grid 256x16), LDS ~27 KB -> target 4-5 blocks/CU.
//   Everything else per R6b (frag-order LDS, A reg-split path, B DMA path).

typedef _Float16 half8 __attribute__((ext_vector_type(8)));
typedef _Float16 half4 __attribute__((ext_vector_type(4)));
typedef float    floatx4 __attribute__((ext_vector_type(4)));

#define C_DIM 256
#define K_CODES 1024
#define HW 1024
#define NPIX 32768
#define NTILES 16         // 1024 / 64
#define USTR 520          // padded unit stride in f16 (512 data + 8 pad)

#define GLOAD_LDS16(g, l) __builtin_amdgcn_global_load_lds(                    \
    (const __attribute__((address_space(1))) unsigned int*)(g),                \
    (__attribute__((address_space(3))) unsigned int*)(l), 16, 0, 0)

// ---------------- kernel 1: normalize codebook + scaled f16 split -----------
__global__ __launch_bounds__(256) void vq_norm_w(const float* __restrict__ w,
                                                 float* __restrict__ w_nT,
                                                 _Float16* __restrict__ wh,
                                                 _Float16* __restrict__ wl) {
    const int row = blockIdx.x;        // 0..1023
    const int t   = threadIdx.x;       // 0..255
    float x = w[row * C_DIM + t];
    float s = x * x;
    #pragma unroll
    for (int off = 32; off > 0; off >>= 1) s += __shfl_down(s, off, 64);
    __shared__ float wsum[4];
    if ((t & 63) == 0) wsum[t >> 6] = s;
    __syncthreads();
    float tot = wsum[0] + wsum[1] + wsum[2] + wsum[3];
    float inv = 1.0f / fmaxf(sqrtf(tot), 1e-12f);
    float y = x * inv;
    w_nT[t * K_CODES + row] = y;       // transposed for finalize's L1-row gather
    float ys = 16.0f * y;
    _Float16 hi = (_Float16)ys;
    wh[row * C_DIM + t] = hi;
    wl[row * C_DIM + t] = (_Float16)(ys - (float)hi);
}

// ---------------- kernel 2: fused split + MFMA GEMM + argmax ----------------
// grid (256 m-tiles, 16 n-tiles), 256 thr = 4 waves 2x2; wave tile 64x32.
// BK=32, 8 phases. A: z fp32 -> reg split -> ds_write_b64 frag-order (8 units).
//                  B: global_load_lds frag-order DMA (2 units/wave, 2 planes).
__global__ __launch_bounds__(256, 4) void vq_gemm(
        const float* __restrict__ z,
        const _Float16* __restrict__ wh, const _Float16* __restrict__ wl,
        float* __restrict__ cand_val, int* __restrict__ cand_idx) {
    __shared__ _Float16 Ah[8 * USTR], Al[8 * USTR];   // 8.3 KB each
    __shared__ _Float16 Bh[4 * USTR], Bl[4 * USTR];   // 4.2 KB each
    __shared__ float red_v[128][2];
    __shared__ int   red_i[128][2];

    const int tid  = threadIdx.x;
    const int lane = tid & 63, wave = tid >> 6;
    const int wm = wave >> 1, wn = wave & 1;
    const int quad = lane >> 4, l15 = lane & 15;
    const int m0 = blockIdx.x * 128, n0 = blockIdx.y * 64;
    const int b  = m0 >> 10, p0 = m0 & 1023;

    // ---- B DMA setup: waves 0,1 -> Bh; waves 2,3 -> Bl; 2 units per wave
    const _Float16* bsrc = (wave < 2) ? wh : wl;
    _Float16*       bdst = (wave < 2) ? Bh : Bl;
    const int ub = (wave & 1) * 2;                 // unit base within plane
    const _Float16* gB[2];
    _Float16*       lB[2];
    #pragma unroll
    for (int i = 0; i < 2; i++) {
        gB[i] = bsrc + (size_t)(n0 + (ub + i) * 16 + l15) * C_DIM + quad * 8;
        lB[i] = bdst + (ub + i) * USTR;
    }

    // ---- A stage setup: wave = k-quad; lane -> (pixel group, k-subgroup)
    const int ap = (lane & 31) * 4;                // local pixel base 0..124
    const int as = lane >> 5;                      // k sub (0,1) -> j base as*4
    const int ak = wave * 8 + as * 4;              // k rel in [0,32)
    const float* zA = z + ((size_t)b * C_DIM + ak) * HW + p0 + ap;

    floatx4 acc[4][2];
    #pragma unroll
    for (int i = 0; i < 4; i++)
        #pragma unroll
        for (int j = 0; j < 2; j++) acc[i][j] = (floatx4){0.f, 0.f, 0.f, 0.f};

    const int afrag = wm * 4, bfrag = wn * 2;

    for (int kt = 0; kt < 8; kt++) {
        __syncthreads();                 // prior iter's frag reads done
        // B DMA (in flight during A load+split below)
        #pragma unroll
        for (int i = 0; i < 2; i++)
            GLOAD_LDS16(gB[i] + kt * 32, lB[i]);
        // A: load 4 rows x 4 pixels fp32, split, write frag-order
        floatx4 za[4];
        #pragma unroll
        for (int r = 0; r < 4; r++)
            za[r] = *(const floatx4*)(zA + (size_t)(kt * 32 + r) * HW);
        #pragma unroll
        for (int i = 0; i < 4; i++) {
            half4 hv, lv;
            #pragma unroll
            for (int r = 0; r < 4; r++) {
                float xv = 4.0f * za[r][i];
                _Float16 h = (_Float16)xv;
                hv[r] = h;
                lv[r] = (_Float16)(xv - (float)h);
            }
            const int p = ap + i;
            const int aidx = (p >> 4) * USTR + wave * 128 + (p & 15) * 8 + as * 4;
            *(half4*)&Ah[aidx] = hv;
            *(half4*)&Al[aidx] = lv;
        }
        __syncthreads();                 // drains vmcnt (B DMA) + lgkm (A writes)

        half8 ah[4], al[4], bh[2], bl[2];
        #pragma unroll
        for (int i = 0; i < 4; i++) {
            ah[i] = *(const half8*)&Ah[(afrag + i) * USTR + lane * 8];
            al[i] = *(const half8*)&Al[(afrag + i) * USTR + lane * 8];
        }
        #pragma unroll
        for (int i = 0; i < 2; i++) {
            bh[i] = *(const half8*)&Bh[(bfrag + i) * USTR + lane * 8];
            bl[i] = *(const half8*)&Bl[(bfrag + i) * USTR + lane * 8];
        }
        #pragma unroll
        for (int mi = 0; mi < 4; mi++)
            #pragma unroll
            for (int ni = 0; ni < 2; ni++) {
                acc[mi][ni] = __builtin_amdgcn_mfma_f32_16x16x32_f16(ah[mi], bh[ni], acc[mi][ni], 0, 0, 0);
                acc[mi][ni] = __builtin_amdgcn_mfma_f32_16x16x32_f16(ah[mi], bl[ni], acc[mi][ni], 0, 0, 0);
                acc[mi][ni] = __builtin_amdgcn_mfma_f32_16x16x32_f16(al[mi], bh[ni], acc[mi][ni], 0, 0, 0);
            }
    }

    // epilogue: per-lane best over ni, shfl-reduce over quad's 16 lanes
    #pragma unroll
    for (int mi = 0; mi < 4; mi++) {
        #pragma unroll
        for (int r = 0; r < 4; r++) {
            float bv = -__builtin_inff();
            int   bi = 0x7fffffff;
            #pragma unroll
            for (int ni = 0; ni < 2; ni++) {
                float v = acc[mi][ni][r];
                int  ci = n0 + wn * 32 + ni * 16 + l15;
                if (v > bv || (v == bv && ci < bi)) { bv = v; bi = ci; }
            }
            #pragma unroll
            for (int mk = 8; mk; mk >>= 1) {
                float ov = __shfl_xor(bv, mk, 16);
                int   oi = __shfl_xor(bi, mk, 16);
                if (ov > bv || (ov == bv && oi < bi)) { bv = ov; bi = oi; }
            }
            if (l15 == 0) {
                int row = wm * 64 + mi * 16 + quad * 4 + r;  // C/D: row=(lane>>4)*4+reg
                red_v[row][wn] = bv;
                red_i[row][wn] = bi;
            }
        }
    }
    __syncthreads();
    if (tid < 128) {
        float bv = red_v[tid][0]; int bi = red_i[tid][0];
        float v2 = red_v[tid][1]; int i2 = red_i[tid][1];
        if (v2 > bv || (v2 == bv && i2 < bi)) { bv = v2; bi = i2; }
        const int pix = m0 + tid;
        cand_val[(size_t)pix * NTILES + blockIdx.y] = bv;
        cand_idx[(size_t)pix * NTILES + blockIdx.y] = bi;
    }
}

// ---------------- kernel 3: reduce candidates + coalesced gather ------------
// grid (32 batches, 8 channel-groups), 256 thr. Coalesced 1KB z_q stores;
// codebook gathered from w_nT so each c-iteration hits one 4KB L1-resident row.
__global__ __launch_bounds__(256) void vq_finalize(
        const float* __restrict__ cand_val,
        const int*   __restrict__ cand_idx,
        const float* __restrict__ w_nT,  // [256][1024]
        float* __restrict__ zq,          // [32][256][1024]
        float* __restrict__ idx_out) {   // [32768] as float
    __shared__ int idx_s[1024];
    const int t  = threadIdx.x;
    const int b  = blockIdx.x;
    const int cg = blockIdx.y;           // channels cg*32 .. +31
    #pragma unroll
    for (int q = 0; q < 4; q++) {
        const int p = q * 256 + t;
        const int n = b * 1024 + p;
        const size_t base = (size_t)n * NTILES;
        float bv = cand_val[base]; int bi = cand_idx[base];
        #pragma unroll
        for (int j = 1; j < NTILES; j++) {
            float v = cand_val[base + j];
            int   c = cand_idx[base + j];
            if (v > bv || (v == bv && c < bi)) { bv = v; bi = c; }
        }
        idx_s[p] = bi;
        if (cg == 0) idx_out[n] = (float)bi;
    }
    __syncthreads();
    float* zqb = zq + (size_t)b * (C_DIM * HW);
    for (int c = 0; c < 32; c++) {
        const int ch = cg * 32 + c;
        const float* wrow = w_nT + (size_t)ch * K_CODES;
        #pragma unroll
        for (int q = 0; q < 4; q++) {
            const int p = q * 256 + t;
            zqb[(size_t)ch * HW + p] = wrow[idx_s[p]];
        }
    }
}

// ---------------- launcher --------------------------------------------------
extern "C" void kernel_launch(void* const* d_in, const int* in_sizes, int n_in,
                              void* d_out, int out_size, void* d_ws, size_t ws_size,
                              hipStream_t stream) {
    const float* z = (const float*)d_in[0];   // 32*256*32*32
    const float* w = (const float*)d_in[1];   // 1024*256
    float* out     = (float*)d_out;           // z_q (8388608) ++ indices (32768)

    char* ws = (char*)d_ws;
    float*    w_nT = (float*)(ws);                       //  0    .. 1 MB
    _Float16* wh   = (_Float16*)(ws + (1u << 20));       //  1 MB .. 1.5 MB
    _Float16* wl   = (_Float16*)(ws + (3u << 19));       //  1.5  .. 2 MB
    float*    cval = (float*)(ws + (2u << 20));          //  2 MB .. 4 MB
    int*      cidx = (int*)(ws + (4u << 20));            //  4 MB .. 6 MB

    vq_norm_w<<<K_CODES, 256, 0, stream>>>(w, w_nT, wh, wl);
    vq_gemm<<<dim3(NPIX / 128, NTILES), 256, 0, stream>>>(z, wh, wl, cval, cidx);
    vq_finalize<<<dim3(32, 8), 256, 0, stream>>>(cval, cidx, w_nT, out, out + 8388608);
}

// Round 9
// 186.230 us; speedup vs baseline: 1.0915x; 1.0915x over previous
//
#include <hip/hip_runtime.h>

// VectorQuantizer, fused: gemm reads z directly (transpose+f16-split in-kernel).
//   wh = f16(16*w_hat), wl = f16(16*w_hat - wh)   (uniform x16: argmax-invariant)
//   zh = f16(4*z),      zl = f16(4*z - zh)        (uniform x4:  argmax-invariant)
//   dot64 = hh + hl + lh  (single f32 accumulator chain; ll ~2^-22 rel, dropped)
// argmin_k ||z_hat - w_hat_k|| == argmax_k <z, w_hat_k>  -> only codebook normalized.
//
// R8: single-barrier K-loop.
//   B: pre-transformed to MFMA-fragment order in GLOBAL memory (whF/wlF, 1 MB,
//      L2-resident) -> per-phase coalesced dwordx4 frag loads, no LDS, no DMA.
//   A: double-buffered frag-order LDS; A(k+1) split+written after MFMA(k);
//      the one barrier per phase publishes it. z loads issue before MFMA.

typedef _Float16 half8 __attribute__((ext_vector_type(8)));
typedef _Float16 half4 __attribute__((ext_vector_type(4)));
typedef float    floatx4 __attribute__((ext_vector_type(4)));

#define C_DIM 256
#define K_CODES 1024
#define HW 1024
#define NPIX 32768
#define NTILES 8          // 1024 / 128
#define USTR 520          // padded unit stride in f16 (512 data + 8 pad)

// ---------------- kernel 1: normalize codebook + scaled f16 split -----------
// Writes w_nT (for finalize gather) and whF/wlF in MFMA B-fragment order:
//   idx = (kt*64 + gu)*512 + (quad*16 + l15)*8 + j
//   where code = gu*16 + l15, k = kt*32 + quad*8 + j.
__global__ __launch_bounds__(256) void vq_norm_w(const float* __restrict__ w,
                                                 float* __restrict__ w_nT,
                                                 _Float16* __restrict__ whF,
                                                 _Float16* __restrict__ wlF) {
    const int row = blockIdx.x;        // code 0..1023
    const int t   = threadIdx.x;       // channel 0..255
    float x = w[row * C_DIM + t];
    float s = x * x;
    #pragma unroll
    for (int off = 32; off > 0; off >>= 1) s += __shfl_down(s, off, 64);
    __shared__ float wsum[4];
    if ((t & 63) == 0) wsum[t >> 6] = s;
    __syncthreads();
    float tot = wsum[0] + wsum[1] + wsum[2] + wsum[3];
    float inv = 1.0f / fmaxf(sqrtf(tot), 1e-12f);
    float y = x * inv;
    w_nT[t * K_CODES + row] = y;       // transposed for finalize's gather
    float ys = 16.0f * y;
    _Float16 hi = (_Float16)ys;
    const int gu = row >> 4, l15 = row & 15;
    const int kt = t >> 5, quad = (t >> 3) & 3, j = t & 7;
    const int idx = (kt * 64 + gu) * 512 + (quad * 16 + l15) * 8 + j;
    whF[idx] = hi;
    wlF[idx] = (_Float16)(ys - (float)hi);
}

// ---------------- kernel 2: fused split + MFMA GEMM + argmax ----------------
// grid (256 m-tiles, 8 n-tiles), 256 thr = 4 waves 2x2; wave tile 64x64.
// BK=32, 8 phases, ONE barrier per phase.
__global__ __launch_bounds__(256, 3) void vq_gemm(
        const float* __restrict__ z,
        const _Float16* __restrict__ whF, const _Float16* __restrict__ wlF,
        float* __restrict__ cand_val, int* __restrict__ cand_idx) {
    __shared__ _Float16 A[2][2][8 * USTR];   // [buf][plane h/l], 16.6 KB per buf
    __shared__ float red_v[128][2];
    __shared__ int   red_i[128][2];

    const int tid  = threadIdx.x;
    const int lane = tid & 63, wave = tid >> 6;
    const int wm = wave >> 1, wn = wave & 1;
    const int quad = lane >> 4, l15 = lane & 15;
    const int m0 = blockIdx.x * 128, n0 = blockIdx.y * 128;
    const int b  = m0 >> 10, p0 = m0 & 1023;

    // ---- A stage mapping (proven in R6b): wave = k-quad; lane -> (pixel, ksub)
    const int ap = (lane & 31) * 4;                // local pixel base 0..124
    const int as = lane >> 5;                      // k sub (0,1)
    const int ak = wave * 8 + as * 4;              // k rel in [0,32)
    const float* zA = z + ((size_t)b * C_DIM + ak) * HW + p0 + ap;
    const int aidx0 = (ap >> 4) * USTR + wave * 128 + (ap & 15) * 8 + as * 4;

    // ---- B frag-order global bases: wave wn covers global units by*8+wn*4+i
    const int gu0 = blockIdx.y * 8 + wn * 4;

    floatx4 acc[4][4];
    #pragma unroll
    for (int i = 0; i < 4; i++)
        #pragma unroll
        for (int j = 0; j < 4; j++) acc[i][j] = (floatx4){0.f, 0.f, 0.f, 0.f};

    const int afrag = wm * 4;

    // ---- prologue: stage A(0) into buf 0
    {
        floatx4 za[4];
        #pragma unroll
        for (int r = 0; r < 4; r++)
            za[r] = *(const floatx4*)(zA + (size_t)r * HW);
        #pragma unroll
        for (int i = 0; i < 4; i++) {
            half4 hv, lv;
            #pragma unroll
            for (int r = 0; r < 4; r++) {
                float xv = 4.0f * za[r][i];
                _Float16 h = (_Float16)xv;
                hv[r] = h;
                lv[r] = (_Float16)(xv - (float)h);
            }
            const int aidx = aidx0 + ((i >> 2) ? 0 : 0) + ((((ap + i) >> 4) - (ap >> 4)) * USTR) + (((ap + i) & 15) - (ap & 15)) * 8;
            *(half4*)&A[0][0][aidx] = hv;
            *(half4*)&A[0][1][aidx] = lv;
        }
    }

    for (int kt = 0; kt < 8; kt++) {
        __syncthreads();                 // publishes A(kt); prior readers done
        const int cb = kt & 1;

        // B frags for kt: coalesced dwordx4 from frag-order global (L2-hot)
        half8 bh[4], bl[4];
        #pragma unroll
        for (int i = 0; i < 4; i++) {
            const size_t bidx = (size_t)(kt * 64 + gu0 + i) * 512 + lane * 8;
            bh[i] = *(const half8*)(whF + bidx);
            bl[i] = *(const half8*)(wlF + bidx);
        }
        // A frags for kt
        half8 ah[4], al[4];
        #pragma unroll
        for (int i = 0; i < 4; i++) {
            ah[i] = *(const half8*)&A[cb][0][(afrag + i) * USTR + lane * 8];
            al[i] = *(const half8*)&A[cb][1][(afrag + i) * USTR + lane * 8];
        }
        // prefetch z(kt+1) — issues before MFMA, latency hidden under it
        floatx4 zan[4];
        if (kt < 7) {
            #pragma unroll
            for (int r = 0; r < 4; r++)
                zan[r] = *(const floatx4*)(zA + (size_t)((kt + 1) * 32 + r) * HW);
        }

        #pragma unroll
        for (int mi = 0; mi < 4; mi++)
            #pragma unroll
            for (int ni = 0; ni < 4; ni++) {
                acc[mi][ni] = __builtin_amdgcn_mfma_f32_16x16x32_f16(ah[mi], bh[ni], acc[mi][ni], 0, 0, 0);
                acc[mi][ni] = __builtin_amdgcn_mfma_f32_16x16x32_f16(ah[mi], bl[ni], acc[mi][ni], 0, 0, 0);
                acc[mi][ni] = __builtin_amdgcn_mfma_f32_16x16x32_f16(al[mi], bh[ni], acc[mi][ni], 0, 0, 0);
            }

        // split + write A(kt+1) into the other buffer (published by next barrier)
        if (kt < 7) {
            const int nb = cb ^ 1;
            #pragma unroll
            for (int i = 0; i < 4; i++) {
                half4 hv, lv;
                #pragma unroll
                for (int r = 0; r < 4; r++) {
                    float xv = 4.0f * zan[r][i];
                    _Float16 h = (_Float16)xv;
                    hv[r] = h;
                    lv[r] = (_Float16)(xv - (float)h);
                }
                const int p = ap + i;
                const int aidx = (p >> 4) * USTR + wave * 128 + (p & 15) * 8 + as * 4;
                *(half4*)&A[nb][0][aidx] = hv;
                *(half4*)&A[nb][1][aidx] = lv;
            }
        }
    }

    // epilogue: per-lane best over ni, shfl-reduce over quad's 16 lanes
    #pragma unroll
    for (int mi = 0; mi < 4; mi++) {
        #pragma unroll
        for (int r = 0; r < 4; r++) {
            float bv = -__builtin_inff();
            int   bi = 0x7fffffff;
            #pragma unroll
            for (int ni = 0; ni < 4; ni++) {
                float v = acc[mi][ni][r];
                int  ci = n0 + (wn * 4 + ni) * 16 + l15;
                if (v > bv || (v == bv && ci < bi)) { bv = v; bi = ci; }
            }
            #pragma unroll
            for (int mk = 8; mk; mk >>= 1) {
                float ov = __shfl_xor(bv, mk, 16);
                int   oi = __shfl_xor(bi, mk, 16);
                if (ov > bv || (ov == bv && oi < bi)) { bv = ov; bi = oi; }
            }
            if (l15 == 0) {
                int row = wm * 64 + mi * 16 + quad * 4 + r;  // C/D: row=(lane>>4)*4+reg
                red_v[row][wn] = bv;
                red_i[row][wn] = bi;
            }
        }
    }
    __syncthreads();
    if (tid < 128) {
        float bv = red_v[tid][0]; int bi = red_i[tid][0];
        float v2 = red_v[tid][1]; int i2 = red_i[tid][1];
        if (v2 > bv || (v2 == bv && i2 < bi)) { bv = v2; bi = i2; }
        const int pix = m0 + tid;
        cand_val[(size_t)pix * NTILES + blockIdx.y] = bv;
        cand_idx[(size_t)pix * NTILES + blockIdx.y] = bi;
    }
}

// ---------------- kernel 3: reduce candidates + coalesced gather ------------
__global__ __launch_bounds__(256) void vq_finalize(
        const float* __restrict__ cand_val,
        const int*   __restrict__ cand_idx,
        const float* __restrict__ w_nT,  // [256][1024]
        float* __restrict__ zq,          // [32][256][1024]
        float* __restrict__ idx_out) {   // [32768] as float
    __shared__ int idx_s[1024];
    const int t  = threadIdx.x;
    const int b  = blockIdx.x;
    const int cg = blockIdx.y;           // channels cg*32 .. +31
    #pragma unroll
    for (int q = 0; q < 4; q++) {
        const int p = q * 256 + t;
        const int n = b * 1024 + p;
        const size_t base = (size_t)n * NTILES;
        float bv = cand_val[base]; int bi = cand_idx[base];
        #pragma unroll
        for (int j = 1; j < NTILES; j++) {
            float v = cand_val[base + j];
            int   c = cand_idx[base + j];
            if (v > bv || (v == bv && c < bi)) { bv = v; bi = c; }
        }
        idx_s[p] = bi;
        if (cg == 0) idx_out[n] = (float)bi;
    }
    __syncthreads();
    float* zqb = zq + (size_t)b * (C_DIM * HW);
    for (int c = 0; c < 32; c++) {
        const int ch = cg * 32 + c;
        const float* wrow = w_nT + (size_t)ch * K_CODES;
        #pragma unroll
        for (int q = 0; q < 4; q++) {
            const int p = q * 256 + t;
            zqb[(size_t)ch * HW + p] = wrow[idx_s[p]];
        }
    }
}

// ---------------- launcher --------------------------------------------------
extern "C" void kernel_launch(void* const* d_in, const int* in_sizes, int n_in,
                              void* d_out, int out_size, void* d_ws, size_t ws_size,
                              hipStream_t stream) {
    const float* z = (const float*)d_in[0];   // 32*256*32*32
    const float* w = (const float*)d_in[1];   // 1024*256
    float* out     = (float*)d_out;           // z_q (8388608) ++ indices (32768)

    char* ws = (char*)d_ws;
    float*    w_nT = (float*)(ws);                       //  0    .. 1 MB
    _Float16* whF  = (_Float16*)(ws + (1u << 20));       //  1 MB .. 1.5 MB
    _Float16* wlF  = (_Float16*)(ws + (3u << 19));       //  1.5  .. 2 MB
    float*    cval = (float*)(ws + (2u << 20));          //  2 MB .. 3 MB
    int*      cidx = (int*)(ws + (3u << 20));            //  3 MB .. 4 MB

    vq_norm_w<<<K_CODES, 256, 0, stream>>>(w, w_nT, whF, wlF);
    vq_gemm<<<dim3(NPIX / 128, NTILES), 256, 0, stream>>>(z, whF, wlF, cval, cidx);
    vq_finalize<<<dim3(32, 8), 256, 0, stream>>>(cval, cidx, w_nT, out, out + 8388608);
}

// Round 10
// 155.863 us; speedup vs baseline: 1.3042x; 1.1948x over previous
//
#include <hip/hip_runtime.h>

// VectorQuantizer, fused: gemm reads z directly (transpose+f16-split in-kernel).
//   wh = f16(16*w_hat), wl = f16(16*w_hat - wh)   (uniform x16: argmax-invariant)
//   zh = f16(4*z),      zl = f16(4*z - zh)        (uniform x4:  argmax-invariant)
//   dot64 = hh + hl + lh  (single f32 accumulator chain; ll ~2^-22 rel, dropped)
// argmin_k ||z_hat - w_hat_k|| == argmax_k <z, w_hat_k>  -> only codebook normalized.
//
// R9: gemm = R6b verbatim (best: 77.9 us). Finalize rebuilt gather-free:
//   per 64-pixel block, read whole codebook rows coalesced (1 KB/row, L2-hot)
//   into padded LDS tile, then write z_q coalesced. No TA-pipe gathers.

typedef _Float16 half8 __attribute__((ext_vector_type(8)));
typedef _Float16 half4 __attribute__((ext_vector_type(4)));
typedef float    floatx4 __attribute__((ext_vector_type(4)));

#define C_DIM 256
#define K_CODES 1024
#define HW 1024
#define NPIX 32768
#define NTILES 8          // 1024 / 128 candidate tiles per pixel
#define USTR 520          // padded unit stride in f16 (512 data + 8 pad)

#define GLOAD_LDS16(g, l) __builtin_amdgcn_global_load_lds(                    \
    (const __attribute__((address_space(1))) unsigned int*)(g),                \
    (__attribute__((address_space(3))) unsigned int*)(l), 16, 0, 0)

// ---------------- kernel 1: normalize codebook + scaled f16 split -----------
__global__ __launch_bounds__(256) void vq_norm_w(const float* __restrict__ w,
                                                 float* __restrict__ w_n,
                                                 _Float16* __restrict__ wh,
                                                 _Float16* __restrict__ wl) {
    const int row = blockIdx.x;        // 0..1023
    const int t   = threadIdx.x;       // 0..255
    float x = w[row * C_DIM + t];
    float s = x * x;
    #pragma unroll
    for (int off = 32; off > 0; off >>= 1) s += __shfl_down(s, off, 64);
    __shared__ float wsum[4];
    if ((t & 63) == 0) wsum[t >> 6] = s;
    __syncthreads();
    float tot = wsum[0] + wsum[1] + wsum[2] + wsum[3];
    float inv = 1.0f / fmaxf(sqrtf(tot), 1e-12f);
    float y = x * inv;
    w_n[row * C_DIM + t] = y;          // ROW-major: finalize reads rows coalesced
    float ys = 16.0f * y;
    _Float16 hi = (_Float16)ys;
    wh[row * C_DIM + t] = hi;
    wl[row * C_DIM + t] = (_Float16)(ys - (float)hi);
}

// ---------------- kernel 2: fused split + MFMA GEMM + argmax (R6b) ----------
// grid (256 m-tiles, 8 n-tiles), 256 thr = 4 waves 2x2; wave tile 64x64.
// BK=32, 8 phases. A: z fp32 -> reg split -> ds_write_b64 frag-order.
//                  B: global_load_lds frag-order DMA (4 units/wave, 2 planes).
__global__ __launch_bounds__(256, 4) void vq_gemm(
        const float* __restrict__ z,
        const _Float16* __restrict__ wh, const _Float16* __restrict__ wl,
        float* __restrict__ cand_val, int* __restrict__ cand_idx) {
    __shared__ _Float16 Ah[8 * USTR], Al[8 * USTR];   // 8.3 KB each
    __shared__ _Float16 Bh[8 * USTR], Bl[8 * USTR];
    __shared__ float red_v[128][2];
    __shared__ int   red_i[128][2];

    const int tid  = threadIdx.x;
    const int lane = tid & 63, wave = tid >> 6;
    const int wm = wave >> 1, wn = wave & 1;
    const int quad = lane >> 4, l15 = lane & 15;
    const int m0 = blockIdx.x * 128, n0 = blockIdx.y * 128;
    const int b  = m0 >> 10, p0 = m0 & 1023;

    // ---- B DMA setup: wave w stages 4 units; planes: w0,w1->Bh  w2,w3->Bl
    const _Float16* bsrc = (wave < 2) ? wh : wl;
    _Float16*       bdst = (wave < 2) ? Bh : Bl;
    const int ub = (wave & 1) * 4;                 // unit base within plane
    const _Float16* gB[4];
    _Float16*       lB[4];
    #pragma unroll
    for (int i = 0; i < 4; i++) {
        gB[i] = bsrc + (size_t)(n0 + (ub + i) * 16 + l15) * C_DIM + quad * 8;
        lB[i] = bdst + (ub + i) * USTR;
    }

    // ---- A stage setup: wave = k-quad; lane -> (pixel group, k-subgroup)
    const int ap = (lane & 31) * 4;                // local pixel base 0..124
    const int as = lane >> 5;                      // k sub (0,1) -> j base as*4
    const int ak = wave * 8 + as * 4;              // k rel in [0,32)
    const float* zA = z + ((size_t)b * C_DIM + ak) * HW + p0 + ap;

    floatx4 acc[4][4];
    #pragma unroll
    for (int i = 0; i < 4; i++)
        #pragma unroll
        for (int j = 0; j < 4; j++) acc[i][j] = (floatx4){0.f, 0.f, 0.f, 0.f};

    const int afrag = wm * 4, bfrag = wn * 4;

    for (int kt = 0; kt < 8; kt++) {
        __syncthreads();                 // prior iter's frag reads done
        // B DMA (in flight during A load+split below)
        #pragma unroll
        for (int i = 0; i < 4; i++)
            GLOAD_LDS16(gB[i] + kt * 32, lB[i]);
        // A: load 4 rows x 4 pixels fp32, split, write frag-order
        floatx4 za[4];
        #pragma unroll
        for (int r = 0; r < 4; r++)
            za[r] = *(const floatx4*)(zA + (size_t)(kt * 32 + r) * HW);
        #pragma unroll
        for (int i = 0; i < 4; i++) {
            half4 hv, lv;
            #pragma unroll
            for (int r = 0; r < 4; r++) {
                float xv = 4.0f * za[r][i];
                _Float16 h = (_Float16)xv;
                hv[r] = h;
                lv[r] = (_Float16)(xv - (float)h);
            }
            const int p = ap + i;
            const int aidx = (p >> 4) * USTR + wave * 128 + (p & 15) * 8 + as * 4;
            *(half4*)&Ah[aidx] = hv;
            *(half4*)&Al[aidx] = lv;
        }
        __syncthreads();                 // drains vmcnt (B DMA) + lgkm (A writes)

        half8 ah[4], al[4], bh[4], bl[4];
        #pragma unroll
        for (int i = 0; i < 4; i++) {
            ah[i] = *(const half8*)&Ah[(afrag + i) * USTR + lane * 8];
            al[i] = *(const half8*)&Al[(afrag + i) * USTR + lane * 8];
            bh[i] = *(const half8*)&Bh[(bfrag + i) * USTR + lane * 8];
            bl[i] = *(const half8*)&Bl[(bfrag + i) * USTR + lane * 8];
        }
        #pragma unroll
        for (int mi = 0; mi < 4; mi++)
            #pragma unroll
            for (int ni = 0; ni < 4; ni++) {
                acc[mi][ni] = __builtin_amdgcn_mfma_f32_16x16x32_f16(ah[mi], bh[ni], acc[mi][ni], 0, 0, 0);
                acc[mi][ni] = __builtin_amdgcn_mfma_f32_16x16x32_f16(ah[mi], bl[ni], acc[mi][ni], 0, 0, 0);
                acc[mi][ni] = __builtin_amdgcn_mfma_f32_16x16x32_f16(al[mi], bh[ni], acc[mi][ni], 0, 0, 0);
            }
    }

    // epilogue: per-lane best over ni, shfl-reduce over quad's 16 lanes
    #pragma unroll
    for (int mi = 0; mi < 4; mi++) {
        #pragma unroll
        for (int r = 0; r < 4; r++) {
            float bv = -__builtin_inff();
            int   bi = 0x7fffffff;
            #pragma unroll
            for (int ni = 0; ni < 4; ni++) {
                float v = acc[mi][ni][r];
                int  ci = n0 + wn * 64 + ni * 16 + l15;
                if (v > bv || (v == bv && ci < bi)) { bv = v; bi = ci; }
            }
            #pragma unroll
            for (int mk = 8; mk; mk >>= 1) {
                float ov = __shfl_xor(bv, mk, 16);
                int   oi = __shfl_xor(bi, mk, 16);
                if (ov > bv || (ov == bv && oi < bi)) { bv = ov; bi = oi; }
            }
            if (l15 == 0) {
                int row = wm * 64 + mi * 16 + quad * 4 + r;  // C/D: row=(lane>>4)*4+reg
                red_v[row][wn] = bv;
                red_i[row][wn] = bi;
            }
        }
    }
    __syncthreads();
    if (tid < 128) {
        float bv = red_v[tid][0]; int bi = red_i[tid][0];
        float v2 = red_v[tid][1]; int i2 = red_i[tid][1];
        if (v2 > bv || (v2 == bv && i2 < bi)) { bv = v2; bi = i2; }
        const int pix = m0 + tid;
        cand_val[(size_t)pix * NTILES + blockIdx.y] = bv;
        cand_idx[(size_t)pix * NTILES + blockIdx.y] = bi;
    }
}

// ---------------- kernel 3: gather-free finalize ----------------------------
// 512 blocks x 64 pixels. (a) reduce 8 candidates/pixel; (b) waves read whole
// codebook rows coalesced (1 KB each, L2-hot) into padded LDS tile;
// (c) coalesced z_q stores (float4 along pixels).
__global__ __launch_bounds__(256) void vq_finalize(
        const float* __restrict__ cand_val,
        const int*   __restrict__ cand_idx,
        const float* __restrict__ w_n,   // [1024][256] row-major
        float* __restrict__ zq,          // [32][256][1024]
        float* __restrict__ idx_out) {   // [32768] as float
    __shared__ float tile[64][257];      // 65.8 KB, +1 pad -> conflict-free
    __shared__ int   idx_s[64];
    const int t    = threadIdx.x;
    const int lane = t & 63, wave = t >> 6;
    const int n0   = blockIdx.x * 64;    // global pixel base
    const int b    = n0 >> 10, p0 = n0 & 1023;

    if (t < 64) {
        const int n = n0 + t;
        const size_t base = (size_t)n * NTILES;
        float bv = cand_val[base]; int bi = cand_idx[base];
        #pragma unroll
        for (int j = 1; j < NTILES; j++) {
            float v = cand_val[base + j];
            int   c = cand_idx[base + j];
            if (v > bv || (v == bv && c < bi)) { bv = v; bi = c; }
        }
        idx_s[t] = bi;
        idx_out[n] = (float)bi;
    }
    __syncthreads();
    // (b) wave w loads rows for pixels w*16..+15: 1 KB coalesced per row
    #pragma unroll
    for (int i = 0; i < 16; i++) {
        const int p = wave * 16 + i;
        const int row = idx_s[p];        // wave-uniform broadcast
        floatx4 v = *(const floatx4*)(w_n + (size_t)row * C_DIM + lane * 4);
        *(floatx4*)&tile[p][lane * 4] = v;
    }
    __syncthreads();
    // (c) stores: float4 along pixels; per wave-store 4 c-values x 64 px
    float* zqb = zq + (size_t)b * (C_DIM * HW) + p0;
    #pragma unroll
    for (int it = 0; it < 16; it++) {
        const int c = it * 16 + wave * 4 + (lane >> 4);   // 0..255
        const int p = (lane & 15) * 4;
        floatx4 v = { tile[p][c], tile[p + 1][c], tile[p + 2][c], tile[p + 3][c] };
        *(floatx4*)(zqb + (size_t)c * HW + p) = v;
    }
}

// ---------------- launcher --------------------------------------------------
extern "C" void kernel_launch(void* const* d_in, const int* in_sizes, int n_in,
                              void* d_out, int out_size, void* d_ws, size_t ws_size,
                              hipStream_t stream) {
    const float* z = (const float*)d_in[0];   // 32*256*32*32
    const float* w = (const float*)d_in[1];   // 1024*256
    float* out     = (float*)d_out;           // z_q (8388608) ++ indices (32768)

    char* ws = (char*)d_ws;
    float*    w_n  = (float*)(ws);                       //  0    .. 1 MB
    _Float16* wh   = (_Float16*)(ws + (1u << 20));       //  1 MB .. 1.5 MB
    _Float16* wl   = (_Float16*)(ws + (3u << 19));       //  1.5  .. 2 MB
    float*    cval = (float*)(ws + (2u << 20));          //  2 MB .. 3 MB
    int*      cidx = (int*)(ws + (3u << 20));            //  3 MB .. 4 MB

    vq_norm_w<<<K_CODES, 256, 0, stream>>>(w, w_n, wh, wl);
    vq_gemm<<<dim3(NPIX / 128, NTILES), 256, 0, stream>>>(z, wh, wl, cval, cidx);
    vq_finalize<<<NPIX / 64, 256, 0, stream>>>(cval, cidx, w_n, out, out + 8388608);
}